// Round 3
// baseline (13290.651 us; speedup 1.0000x reference)
//
#include <hip/hip_runtime.h>
#include <hip/hip_bf16.h>

#define SEQ 4096
#define EMB 1024
#define HID 2048
#define G4  8192
#define NL  256

typedef __attribute__((ext_vector_type(8))) short bf16x8;
typedef __attribute__((ext_vector_type(4))) float f32x4;

static __device__ __forceinline__ unsigned short f2bf(float f) {
    unsigned int x = __builtin_bit_cast(unsigned int, f);
    return (unsigned short)((x + 0x7FFFu + ((x >> 16) & 1u)) >> 16);
}
static __device__ __forceinline__ float bf2f(unsigned short u) {
    return __builtin_bit_cast(float, ((unsigned int)u) << 16);
}
static __device__ __forceinline__ unsigned long long aload(const unsigned long long* p) {
    return __hip_atomic_load(p, __ATOMIC_RELAXED, __HIP_MEMORY_SCOPE_AGENT);
}
static __device__ __forceinline__ float frcp(float x) {
    return __builtin_amdgcn_rcpf(x);
}
static __device__ __forceinline__ float fsigm(float x) {
    return frcp(1.f + __expf(-x));
}
static __device__ __forceinline__ float ftanh(float x) {
    return 1.f - 2.f * frcp(__expf(2.f * x) + 1.f);
}

// ---------------- fp32 -> bf16 convert ----------------
__global__ __launch_bounds__(256) void k_f2b(const float* __restrict__ in,
                                             unsigned short* __restrict__ out, int n) {
    int i = (blockIdx.x * 256 + threadIdx.x) * 4;
    if (i < n) {
        float4 v = *(const float4*)&in[i];
        ushort4 u;
        u.x = f2bf(v.x); u.y = f2bf(v.y); u.z = f2bf(v.z); u.w = f2bf(v.w);
        *(ushort4*)&out[i] = u;
    }
}

// ---------------- embedding gather + cast ----------------
__global__ __launch_bounds__(256) void k_emb(const int* __restrict__ ids,
                                             const float* __restrict__ W_emb,
                                             unsigned short* __restrict__ out) {
    int t = blockIdx.x;
    int e0 = threadIdx.x * 4;
    const float4 v = *(const float4*)&W_emb[(size_t)ids[t] * EMB + e0];
    ushort4 u;
    u.x = f2bf(v.x); u.y = f2bf(v.y); u.z = f2bf(v.z); u.w = f2bf(v.w);
    *(ushort4*)&out[(size_t)t * EMB + e0] = u;
}

// ---------------- bf16 MFMA GEMM:  C[M,N] = A[M,K] * B[N,K]^T + bias ----------------
// Cb path is used ONLY for the xg precompute (N==G4): stores are swizzled to
// [t][unit][gate] layout (u*4+q) so k_lstm's per-step prefetch is one 8B load.
#define BM 128
#define BN 128
#define BK 32
__global__ __launch_bounds__(256) void k_gemm_bt(
    const unsigned short* __restrict__ A, const unsigned short* __restrict__ B,
    const float* __restrict__ bias1, const float* __restrict__ bias2,
    float* __restrict__ Cf, unsigned short* __restrict__ Cb,
    int M, int N, int K)
{
    __shared__ unsigned short As[BM * BK];
    __shared__ unsigned short Bs[BN * BK];
    const int bm = blockIdx.x * BM;
    const int bn = blockIdx.y * BN;
    const int tid = threadIdx.x;
    const int wave = tid >> 6, lane = tid & 63;
    const int wm = (wave & 1) * 64, wn = (wave >> 1) * 64;
    const int row16 = lane & 15, quad = lane >> 4;

    f32x4 acc[4][4];
#pragma unroll
    for (int i = 0; i < 4; ++i)
#pragma unroll
        for (int j = 0; j < 4; ++j) acc[i][j] = (f32x4){0.f, 0.f, 0.f, 0.f};

    for (int k0 = 0; k0 < K; k0 += BK) {
        __syncthreads();
#pragma unroll
        for (int s = 0; s < 2; ++s) {
            int c = tid + s * 256;
            int r = c >> 2, col = (c & 3) * 8;
            *(uint4*)&As[r * BK + col] = *(const uint4*)&A[(size_t)(bm + r) * K + k0 + col];
            *(uint4*)&Bs[r * BK + col] = *(const uint4*)&B[(size_t)(bn + r) * K + k0 + col];
        }
        __syncthreads();
        bf16x8 af[4], bfr[4];
#pragma unroll
        for (int i = 0; i < 4; ++i) {
            af[i]  = *(const bf16x8*)&As[(wm + i * 16 + row16) * BK + quad * 8];
            bfr[i] = *(const bf16x8*)&Bs[(wn + i * 16 + row16) * BK + quad * 8];
        }
#pragma unroll
        for (int i = 0; i < 4; ++i)
#pragma unroll
            for (int j = 0; j < 4; ++j)
                acc[i][j] = __builtin_amdgcn_mfma_f32_16x16x32_bf16(af[i], bfr[j], acc[i][j], 0, 0, 0);
    }

#pragma unroll
    for (int j = 0; j < 4; ++j) {
        int col = bn + wn + j * 16 + row16;
        float bsum = (bias1 ? bias1[col] : 0.f) + (bias2 ? bias2[col] : 0.f);
#pragma unroll
        for (int i = 0; i < 4; ++i) {
#pragma unroll
            for (int r = 0; r < 4; ++r) {
                int row = bm + wm + i * 16 + quad * 4 + r;
                float v = acc[i][j][r] + bsum;
                if (Cf) Cf[(size_t)row * N + col] = v;
                else    Cb[(size_t)row * N + ((col & 2047) << 2) + (col >> 11)] = f2bf(v);
            }
        }
    }
}

// ---------------- persistent LSTM recurrence (register-direct MFMA) ----------------
// r3: revert to r1 geometry (256 blocks x 1024 thr, 8 units/block, plain relaxed
// atomic-store publish — best measured config, 9.99ms). Single change: the poll
// loop is a ROTATING 4-DEEP PIPELINE — 4 same-address loads continuously in
// flight, check-and-reissue one at a time. Steady state: one poll RETURNS every
// RT/4 cycles, so detection happens ~RT/8 after store visibility instead of
// ~RT/2 + sleep (r1's backoff loop re-issued only after a full vmcnt-serialized
// round trip). No sleeps. r1/r2 proved poll TRAFFIC is irrelevant (FETCH down
// 27%/36%, time flat/worse) — this spends traffic to buy latency.
// Keep from r2: rcp-based activations (shorter serial activation chain).
#define LSTM_LDS 90112
__global__ __launch_bounds__(1024, 1) void k_lstm(
    const unsigned short* __restrict__ Whhb, // [8192,2048] bf16
    const unsigned short* __restrict__ xg,   // [4096][2048 units][4 gates] bf16
    const float* __restrict__ h0, const float* __restrict__ c0,
    unsigned short* __restrict__ hsb,        // [4096,2048] bf16
    float* __restrict__ outHC,               // d_out + SEQ*NL : [hL(2048), cL(2048)]
    unsigned long long* __restrict__ hcomm)  // [2][8 replicas][1024] tagged words
{
    extern __shared__ char smem[];
    float* LDSp = (float*)smem;              // 2 buffers x [32 rows][stride 20]

    const int b = blockIdx.x, tid = threadIdx.x;
    const int wave = tid >> 6, lane = tid & 63;
    const int sub = lane & 15, quad = lane >> 4;

    const int qa = (sub >> 3), qb = 2 + (sub >> 3), j = sub & 7;
    const unsigned short* wa = Whhb + ((size_t)(qa * HID + b * 8 + j)) * HID + wave * 128 + quad * 8;
    const unsigned short* wb = Whhb + ((size_t)(qb * HID + b * 8 + j)) * HID + wave * 128 + quad * 8;
    bf16x8 afrA[4], afrB[4];
#pragma unroll
    for (int c = 0; c < 4; ++c) {
        afrA[c] = *(const bf16x8*)(wa + c * 32);
        afrB[c] = *(const bf16x8*)(wb + c * 32);
    }

    float creg = 0.f;
    if (tid < 8) creg = c0[b * 8 + tid];

    for (int t = 0; t < SEQ; ++t) {
        // wave0 activation lanes prefetch their 4 x-gate values (one 8B load)
        float xq0 = 0.f, xq1 = 0.f, xq2 = 0.f, xq3 = 0.f;
        if (wave == 0 && lane < 8) {
            uint2 w2 = *(const uint2*)(xg + (size_t)t * G4 + (size_t)(b * 8 + lane) * 4);
            xq0 = bf2f((unsigned short)(w2.x & 0xffff));
            xq1 = bf2f((unsigned short)(w2.x >> 16));
            xq2 = bf2f((unsigned short)(w2.y & 0xffff));
            xq3 = bf2f((unsigned short)(w2.y >> 16));
        }

        f32x4 accA0 = (f32x4){0.f, 0.f, 0.f, 0.f};
        f32x4 accA1 = (f32x4){0.f, 0.f, 0.f, 0.f};
        f32x4 accB0 = (f32x4){0.f, 0.f, 0.f, 0.f};
        f32x4 accB1 = (f32x4){0.f, 0.f, 0.f, 0.f};

        if (t == 0) {
#pragma unroll
            for (int c = 0; c < 4; ++c) {
                const float* hp = h0 + wave * 128 + c * 32 + quad * 8;
                float4 va = *(const float4*)hp;
                float4 vb = *(const float4*)(hp + 4);
                uint4 d;
                d.x = (unsigned)f2bf(va.x) | ((unsigned)f2bf(va.y) << 16);
                d.y = (unsigned)f2bf(va.z) | ((unsigned)f2bf(va.w) << 16);
                d.z = (unsigned)f2bf(vb.x) | ((unsigned)f2bf(vb.y) << 16);
                d.w = (unsigned)f2bf(vb.z) | ((unsigned)f2bf(vb.w) << 16);
                bf16x8 hf = __builtin_bit_cast(bf16x8, d);
                if (c < 2) {
                    accA0 = __builtin_amdgcn_mfma_f32_16x16x32_bf16(afrA[c], hf, accA0, 0, 0, 0);
                    accB0 = __builtin_amdgcn_mfma_f32_16x16x32_bf16(afrB[c], hf, accB0, 0, 0, 0);
                } else {
                    accA1 = __builtin_amdgcn_mfma_f32_16x16x32_bf16(afrA[c], hf, accA1, 0, 0, 0);
                    accB1 = __builtin_amdgcn_mfma_f32_16x16x32_bf16(afrB[c], hf, accB1, 0, 0, 0);
                }
            }
        } else {
            // lane L polls its own word in THIS block's replica (b&7).
            // Rotating 4-deep pipelined poll: 4 same-address loads in flight,
            // check oldest / reissue / check next — one poll RETURN per RT/4.
            const unsigned long long* sp =
                hcomm + (size_t)((t - 1) & 1) * 8192 + (size_t)(b & 7) * 1024 + wave * 64 + lane;
            const unsigned tag = (unsigned)t;
            unsigned long long x;
            unsigned long long p0 = aload(sp), p1 = aload(sp), p2 = aload(sp), p3 = aload(sp);
            for (;;) {
                if ((unsigned)(p0 >> 32) == tag) { x = p0; break; }
                p0 = aload(sp);
                if ((unsigned)(p1 >> 32) == tag) { x = p1; break; }
                p1 = aload(sp);
                if ((unsigned)(p2 >> 32) == tag) { x = p2; break; }
                p2 = aload(sp);
                if ((unsigned)(p3 >> 32) == tag) { x = p3; break; }
                p3 = aload(sp);
            }
            int myd = (int)(unsigned)x;
#pragma unroll
            for (int c = 0; c < 4; ++c) {
                const int sl = c * 16 + quad * 4;
                uint4 d;
                d.x = (unsigned)__shfl(myd, sl + 0);
                d.y = (unsigned)__shfl(myd, sl + 1);
                d.z = (unsigned)__shfl(myd, sl + 2);
                d.w = (unsigned)__shfl(myd, sl + 3);
                bf16x8 hf = __builtin_bit_cast(bf16x8, d);
                if (c < 2) {
                    accA0 = __builtin_amdgcn_mfma_f32_16x16x32_bf16(afrA[c], hf, accA0, 0, 0, 0);
                    accB0 = __builtin_amdgcn_mfma_f32_16x16x32_bf16(afrB[c], hf, accB0, 0, 0, 0);
                } else {
                    accA1 = __builtin_amdgcn_mfma_f32_16x16x32_bf16(afrA[c], hf, accA1, 0, 0, 0);
                    accB1 = __builtin_amdgcn_mfma_f32_16x16x32_bf16(afrB[c], hf, accB1, 0, 0, 0);
                }
            }
        }
        f32x4 acc0 = accA0 + accA1;
        f32x4 acc1 = accB0 + accB1;

        // partials -> double-buffered LDS, ONE barrier per step.
        float* P = LDSp + (t & 1) * 640;
        if (sub == 0) {
#pragma unroll
            for (int r = 0; r < 4; ++r) {
                P[(quad * 4 + r) * 20 + wave]      = acc0[r];
                P[(16 + quad * 4 + r) * 20 + wave] = acc1[r];
            }
        }
        __syncthreads();

        if (wave == 0) {
            __builtin_amdgcn_s_setprio(1);
            float g = 0.f;
            if (lane < 32) {
                const float* rp = P + lane * 20;
                f32x4 s = *(const f32x4*)rp;
                s += *(const f32x4*)(rp + 4);
                s += *(const f32x4*)(rp + 8);
                s += *(const f32x4*)(rp + 12);
                g = s[0] + s[1] + s[2] + s[3];
            }
            float gF = __shfl(g, 8 + lane);
            float gG = __shfl(g, 16 + lane);
            float gO = __shfl(g, 24 + lane);
            unsigned hv = 0;
            float cn = 0.f, hn = 0.f;
            if (lane < 8) {
                float gi = g  + xq0;
                float gf = gF + xq1;
                float gg = gG + xq2;
                float go = gO + xq3;
                float i_ = fsigm(gi);
                float f_ = fsigm(gf);
                float g_ = ftanh(gg);
                float o_ = fsigm(go);
                cn = f_ * creg + i_ * g_;
                hn = o_ * ftanh(cn);
                creg = cn;
                hv = (unsigned)f2bf(hn);
            }
            {
                int jj = lane & 3;
                unsigned lo = (unsigned)__shfl((int)hv, 2 * jj);
                unsigned hi = (unsigned)__shfl((int)hv, 2 * jj + 1);
                if (lane < 32) {
                    unsigned long long wrd =
                        (((unsigned long long)(unsigned)(t + 1)) << 32)
                        | (unsigned long long)(lo | (hi << 16));
                    __hip_atomic_store(
                        &hcomm[(size_t)(t & 1) * 8192 + (size_t)(lane >> 2) * 1024 + b * 4 + jj],
                        wrd, __ATOMIC_RELAXED, __HIP_MEMORY_SCOPE_AGENT);
                }
            }
            __builtin_amdgcn_s_setprio(0);
            if (lane < 8) {
                hsb[(size_t)t * HID + b * 8 + lane] = (unsigned short)hv;
                if (t == SEQ - 1) {
                    outHC[b * 8 + lane] = hn;
                    outHC[HID + b * 8 + lane] = cn;
                }
            }
        }
    }
}

// ---------------- relu + log_softmax over rows of 256 ----------------
__global__ __launch_bounds__(256) void k_softmax(const float* __restrict__ logits,
                                                 float* __restrict__ out) {
    int row = blockIdx.x * 4 + (threadIdx.x >> 6);
    int lane = threadIdx.x & 63;
    const float* Lr = logits + (size_t)row * NL;
    float4 v = *(const float4*)&Lr[lane * 4];
    v.x = fmaxf(v.x, 0.f); v.y = fmaxf(v.y, 0.f);
    v.z = fmaxf(v.z, 0.f); v.w = fmaxf(v.w, 0.f);
    float m = fmaxf(fmaxf(v.x, v.y), fmaxf(v.z, v.w));
#pragma unroll
    for (int off = 32; off > 0; off >>= 1) m = fmaxf(m, __shfl_xor(m, off));
    float e = __expf(v.x - m) + __expf(v.y - m) + __expf(v.z - m) + __expf(v.w - m);
#pragma unroll
    for (int off = 32; off > 0; off >>= 1) e += __shfl_xor(e, off);
    float ls = __logf(e) + m;
    float4 o;
    o.x = v.x - ls; o.y = v.y - ls; o.z = v.z - ls; o.w = v.w - ls;
    *(float4*)&out[(size_t)row * NL + lane * 4] = o;
}

extern "C" void kernel_launch(void* const* d_in, const int* in_sizes, int n_in,
                              void* d_out, int out_size, void* d_ws, size_t ws_size,
                              hipStream_t stream) {
    const int*   ids   = (const int*)d_in[0];
    const float* h0    = (const float*)d_in[1];
    const float* c0    = (const float*)d_in[2];
    const float* W_emb = (const float*)d_in[3];
    const float* W_ih  = (const float*)d_in[4];
    const float* W_hh  = (const float*)d_in[5];
    const float* b_ih  = (const float*)d_in[6];
    const float* b_hh  = (const float*)d_in[7];
    const float* W_out = (const float*)d_in[8];
    const float* b_out = (const float*)d_in[9];
    float* out = (float*)d_out;

    char* ws = (char*)d_ws;
    unsigned short* xg    = (unsigned short*)(ws);                 // 64MB  [4096][2048u][4q] bf16
    unsigned short* hsb   = (unsigned short*)(ws + 67108864);      // 16MB  [4096,2048] bf16
    unsigned short* Wihb  = (unsigned short*)(ws + 83886080);      // 16MB
    unsigned short* embb  = (unsigned short*)(ws + 100663296);     // 8MB
    unsigned short* Woutb = (unsigned short*)(ws + 109051904);     // 1MB
    float*          logit = (float*)(ws + 110100480);              // 4MB
    unsigned short* Whhb  = (unsigned short*)(ws + 114294784);     // 32MB [8192,2048] bf16
    unsigned long long* hcomm = (unsigned long long*)(ws + 147849216); // 128KB (0xAA poison != any tag)

    k_f2b<<<(G4 * EMB / 4 + 255) / 256, 256, 0, stream>>>(W_ih, Wihb, G4 * EMB);
    k_f2b<<<(NL * HID / 4 + 255) / 256, 256, 0, stream>>>(W_out, Woutb, NL * HID);
    k_f2b<<<(G4 * HID / 4 + 255) / 256, 256, 0, stream>>>(W_hh, Whhb, G4 * HID);
    k_emb<<<SEQ, 256, 0, stream>>>(ids, W_emb, embb);

    dim3 g1(SEQ / BM, G4 / BN);
    k_gemm_bt<<<g1, 256, 0, stream>>>(embb, Wihb, b_ih, b_hh, nullptr, xg, SEQ, G4, EMB);

    hipFuncSetAttribute((const void*)k_lstm, hipFuncAttributeMaxDynamicSharedMemorySize, LSTM_LDS);
    k_lstm<<<256, 1024, LSTM_LDS, stream>>>(Whhb, xg, h0, c0, hsb, out + (size_t)SEQ * NL, hcomm);

    dim3 g2(SEQ / BM, NL / BN);
    k_gemm_bt<<<g2, 256, 0, stream>>>(hsb, Woutb, b_out, nullptr, logit, nullptr, SEQ, NL, HID);

    k_softmax<<<SEQ / 4, 256, 0, stream>>>(logit, out);
}

// Round 4
// 9610.514 us; speedup vs baseline: 1.3829x; 1.3829x over previous
//
#include <hip/hip_runtime.h>
#include <hip/hip_bf16.h>

#define SEQ 4096
#define EMB 1024
#define HID 2048
#define G4  8192
#define NL  256

typedef __attribute__((ext_vector_type(8))) short bf16x8;
typedef __attribute__((ext_vector_type(4))) float f32x4;

static __device__ __forceinline__ unsigned short f2bf(float f) {
    unsigned int x = __builtin_bit_cast(unsigned int, f);
    return (unsigned short)((x + 0x7FFFu + ((x >> 16) & 1u)) >> 16);
}
static __device__ __forceinline__ float bf2f(unsigned short u) {
    return __builtin_bit_cast(float, ((unsigned int)u) << 16);
}
static __device__ __forceinline__ unsigned long long aload(const unsigned long long* p) {
    return __hip_atomic_load(p, __ATOMIC_RELAXED, __HIP_MEMORY_SCOPE_AGENT);
}
static __device__ __forceinline__ float frcp(float x) {
    return __builtin_amdgcn_rcpf(x);
}
static __device__ __forceinline__ float fsigm(float x) {
    return frcp(1.f + __expf(-x));
}
static __device__ __forceinline__ float ftanh(float x) {
    return 1.f - 2.f * frcp(__expf(2.f * x) + 1.f);
}

// ---------------- fp32 -> bf16 convert ----------------
__global__ __launch_bounds__(256) void k_f2b(const float* __restrict__ in,
                                             unsigned short* __restrict__ out, int n) {
    int i = (blockIdx.x * 256 + threadIdx.x) * 4;
    if (i < n) {
        float4 v = *(const float4*)&in[i];
        ushort4 u;
        u.x = f2bf(v.x); u.y = f2bf(v.y); u.z = f2bf(v.z); u.w = f2bf(v.w);
        *(ushort4*)&out[i] = u;
    }
}

// ---------------- embedding gather + cast ----------------
__global__ __launch_bounds__(256) void k_emb(const int* __restrict__ ids,
                                             const float* __restrict__ W_emb,
                                             unsigned short* __restrict__ out) {
    int t = blockIdx.x;
    int e0 = threadIdx.x * 4;
    const float4 v = *(const float4*)&W_emb[(size_t)ids[t] * EMB + e0];
    ushort4 u;
    u.x = f2bf(v.x); u.y = f2bf(v.y); u.z = f2bf(v.z); u.w = f2bf(v.w);
    *(ushort4*)&out[(size_t)t * EMB + e0] = u;
}

// ---------------- bf16 MFMA GEMM:  C[M,N] = A[M,K] * B[N,K]^T + bias ----------------
// Cb path is used ONLY for the xg precompute (N==G4): stores are swizzled to
// [t][unit][gate] layout (u*4+q) so k_lstm's per-step prefetch is one 8B load.
#define BM 128
#define BN 128
#define BK 32
__global__ __launch_bounds__(256) void k_gemm_bt(
    const unsigned short* __restrict__ A, const unsigned short* __restrict__ B,
    const float* __restrict__ bias1, const float* __restrict__ bias2,
    float* __restrict__ Cf, unsigned short* __restrict__ Cb,
    int M, int N, int K)
{
    __shared__ unsigned short As[BM * BK];
    __shared__ unsigned short Bs[BN * BK];
    const int bm = blockIdx.x * BM;
    const int bn = blockIdx.y * BN;
    const int tid = threadIdx.x;
    const int wave = tid >> 6, lane = tid & 63;
    const int wm = (wave & 1) * 64, wn = (wave >> 1) * 64;
    const int row16 = lane & 15, quad = lane >> 4;

    f32x4 acc[4][4];
#pragma unroll
    for (int i = 0; i < 4; ++i)
#pragma unroll
        for (int j = 0; j < 4; ++j) acc[i][j] = (f32x4){0.f, 0.f, 0.f, 0.f};

    for (int k0 = 0; k0 < K; k0 += BK) {
        __syncthreads();
#pragma unroll
        for (int s = 0; s < 2; ++s) {
            int c = tid + s * 256;
            int r = c >> 2, col = (c & 3) * 8;
            *(uint4*)&As[r * BK + col] = *(const uint4*)&A[(size_t)(bm + r) * K + k0 + col];
            *(uint4*)&Bs[r * BK + col] = *(const uint4*)&B[(size_t)(bn + r) * K + k0 + col];
        }
        __syncthreads();
        bf16x8 af[4], bfr[4];
#pragma unroll
        for (int i = 0; i < 4; ++i) {
            af[i]  = *(const bf16x8*)&As[(wm + i * 16 + row16) * BK + quad * 8];
            bfr[i] = *(const bf16x8*)&Bs[(wn + i * 16 + row16) * BK + quad * 8];
        }
#pragma unroll
        for (int i = 0; i < 4; ++i)
#pragma unroll
            for (int j = 0; j < 4; ++j)
                acc[i][j] = __builtin_amdgcn_mfma_f32_16x16x32_bf16(af[i], bfr[j], acc[i][j], 0, 0, 0);
    }

#pragma unroll
    for (int j = 0; j < 4; ++j) {
        int col = bn + wn + j * 16 + row16;
        float bsum = (bias1 ? bias1[col] : 0.f) + (bias2 ? bias2[col] : 0.f);
#pragma unroll
        for (int i = 0; i < 4; ++i) {
#pragma unroll
            for (int r = 0; r < 4; ++r) {
                int row = bm + wm + i * 16 + quad * 4 + r;
                float v = acc[i][j][r] + bsum;
                if (Cf) Cf[(size_t)row * N + col] = v;
                else    Cb[(size_t)row * N + ((col & 2047) << 2) + (col >> 11)] = f2bf(v);
            }
        }
    }
}

// ---------------- persistent LSTM recurrence (register-direct MFMA) ----------------
// r4 = exact r1 revert (256 blocks x 1024 thr, 8 units/block, backoff poll,
// plain relaxed atomic-store publish — best measured, 9.99ms) + ONE change:
// PADDED LINE-EXCLUSIVE MAILBOX. r1's layout packed 2 producer blocks (on 2
// different XCDs) into each 64B line -> two invalidate/update events per line
// per step through the IC directory + consumers refetching half-written lines.
// New layout [2 phases][8 replicas][256 producers][8-word line]: each producer
// owns a full 64B line per replica (writes slots 0-3, slots 4-7 pad).
// Consumer unit mapping is IDENTICAL (lane l still gets h[wave*128+2l,+1]):
//   producer p = wave*16 + (l>>2), slot = l&3  ->  units p*8+2*slot = wave*128+2l.
// Counters that led here: FETCH ~450B/step/block proves polls are served by
// the XCD-shared L2 (replica b&7 == XCD b%8 -> 32 sibling blocks share the
// refetched line); VALUBusy reconciles at full 2.4GHz. The remaining cost is
// store->IC+invalidate, one refetch RT/line/XCD, detect quantum, and skew.
// Keep rcp-based activations (r2/r3, numerics unchanged).
#define LSTM_LDS 90112
__global__ __launch_bounds__(1024, 1) void k_lstm(
    const unsigned short* __restrict__ Whhb, // [8192,2048] bf16
    const unsigned short* __restrict__ xg,   // [4096][2048 units][4 gates] bf16
    const float* __restrict__ h0, const float* __restrict__ c0,
    unsigned short* __restrict__ hsb,        // [4096,2048] bf16
    float* __restrict__ outHC,               // d_out + SEQ*NL : [hL(2048), cL(2048)]
    unsigned long long* __restrict__ hcomm)  // [2][8][256][8] tagged words, 256KB
{
    extern __shared__ char smem[];
    float* LDSp = (float*)smem;              // 2 buffers x [32 rows][stride 20]

    const int b = blockIdx.x, tid = threadIdx.x;
    const int wave = tid >> 6, lane = tid & 63;
    const int sub = lane & 15, quad = lane >> 4;

    const int qa = (sub >> 3), qb = 2 + (sub >> 3), j = sub & 7;
    const unsigned short* wa = Whhb + ((size_t)(qa * HID + b * 8 + j)) * HID + wave * 128 + quad * 8;
    const unsigned short* wb = Whhb + ((size_t)(qb * HID + b * 8 + j)) * HID + wave * 128 + quad * 8;
    bf16x8 afrA[4], afrB[4];
#pragma unroll
    for (int c = 0; c < 4; ++c) {
        afrA[c] = *(const bf16x8*)(wa + c * 32);
        afrB[c] = *(const bf16x8*)(wb + c * 32);
    }

    float creg = 0.f;
    if (tid < 8) creg = c0[b * 8 + tid];

    for (int t = 0; t < SEQ; ++t) {
        // wave0 activation lanes prefetch their 4 x-gate values (one 8B load)
        float xq0 = 0.f, xq1 = 0.f, xq2 = 0.f, xq3 = 0.f;
        if (wave == 0 && lane < 8) {
            uint2 w2 = *(const uint2*)(xg + (size_t)t * G4 + (size_t)(b * 8 + lane) * 4);
            xq0 = bf2f((unsigned short)(w2.x & 0xffff));
            xq1 = bf2f((unsigned short)(w2.x >> 16));
            xq2 = bf2f((unsigned short)(w2.y & 0xffff));
            xq3 = bf2f((unsigned short)(w2.y >> 16));
        }

        f32x4 accA0 = (f32x4){0.f, 0.f, 0.f, 0.f};
        f32x4 accA1 = (f32x4){0.f, 0.f, 0.f, 0.f};
        f32x4 accB0 = (f32x4){0.f, 0.f, 0.f, 0.f};
        f32x4 accB1 = (f32x4){0.f, 0.f, 0.f, 0.f};

        if (t == 0) {
#pragma unroll
            for (int c = 0; c < 4; ++c) {
                const float* hp = h0 + wave * 128 + c * 32 + quad * 8;
                float4 va = *(const float4*)hp;
                float4 vb = *(const float4*)(hp + 4);
                uint4 d;
                d.x = (unsigned)f2bf(va.x) | ((unsigned)f2bf(va.y) << 16);
                d.y = (unsigned)f2bf(va.z) | ((unsigned)f2bf(va.w) << 16);
                d.z = (unsigned)f2bf(vb.x) | ((unsigned)f2bf(vb.y) << 16);
                d.w = (unsigned)f2bf(vb.z) | ((unsigned)f2bf(vb.w) << 16);
                bf16x8 hf = __builtin_bit_cast(bf16x8, d);
                if (c < 2) {
                    accA0 = __builtin_amdgcn_mfma_f32_16x16x32_bf16(afrA[c], hf, accA0, 0, 0, 0);
                    accB0 = __builtin_amdgcn_mfma_f32_16x16x32_bf16(afrB[c], hf, accB0, 0, 0, 0);
                } else {
                    accA1 = __builtin_amdgcn_mfma_f32_16x16x32_bf16(afrA[c], hf, accA1, 0, 0, 0);
                    accB1 = __builtin_amdgcn_mfma_f32_16x16x32_bf16(afrB[c], hf, accB1, 0, 0, 0);
                }
            }
        } else {
            // lane l polls producer p = wave*16 + (l>>2), slot l&3 in THIS
            // block's replica (b&7). r1 backoff structure: 1 probe (late waves
            // hit immediately), sleep(8) [~512cy], then 2-load rounds + sleep(1).
            const unsigned long long* sp =
                hcomm + (size_t)((t - 1) & 1) * 16384 + (size_t)(b & 7) * 2048
                      + (size_t)(wave * 16 + (lane >> 2)) * 8 + (lane & 3);
            const unsigned tag = (unsigned)t;
            unsigned long long x = aload(sp);
            if ((unsigned)(x >> 32) != tag) {
                __builtin_amdgcn_s_sleep(8);
                for (;;) {
                    unsigned long long x1 = aload(sp);
                    unsigned long long x2 = aload(sp);
                    if ((unsigned)(x1 >> 32) == tag) { x = x1; break; }
                    if ((unsigned)(x2 >> 32) == tag) { x = x2; break; }
                    __builtin_amdgcn_s_sleep(1);
                }
            }
            int myd = (int)(unsigned)x;
#pragma unroll
            for (int c = 0; c < 4; ++c) {
                const int sl = c * 16 + quad * 4;
                uint4 d;
                d.x = (unsigned)__shfl(myd, sl + 0);
                d.y = (unsigned)__shfl(myd, sl + 1);
                d.z = (unsigned)__shfl(myd, sl + 2);
                d.w = (unsigned)__shfl(myd, sl + 3);
                bf16x8 hf = __builtin_bit_cast(bf16x8, d);
                if (c < 2) {
                    accA0 = __builtin_amdgcn_mfma_f32_16x16x32_bf16(afrA[c], hf, accA0, 0, 0, 0);
                    accB0 = __builtin_amdgcn_mfma_f32_16x16x32_bf16(afrB[c], hf, accB0, 0, 0, 0);
                } else {
                    accA1 = __builtin_amdgcn_mfma_f32_16x16x32_bf16(afrA[c], hf, accA1, 0, 0, 0);
                    accB1 = __builtin_amdgcn_mfma_f32_16x16x32_bf16(afrB[c], hf, accB1, 0, 0, 0);
                }
            }
        }
        f32x4 acc0 = accA0 + accA1;
        f32x4 acc1 = accB0 + accB1;

        // partials -> double-buffered LDS, ONE barrier per step.
        float* P = LDSp + (t & 1) * 640;
        if (sub == 0) {
#pragma unroll
            for (int r = 0; r < 4; ++r) {
                P[(quad * 4 + r) * 20 + wave]      = acc0[r];
                P[(16 + quad * 4 + r) * 20 + wave] = acc1[r];
            }
        }
        __syncthreads();

        if (wave == 0) {
            __builtin_amdgcn_s_setprio(1);
            float g = 0.f;
            if (lane < 32) {
                const float* rp = P + lane * 20;
                f32x4 s = *(const f32x4*)rp;
                s += *(const f32x4*)(rp + 4);
                s += *(const f32x4*)(rp + 8);
                s += *(const f32x4*)(rp + 12);
                g = s[0] + s[1] + s[2] + s[3];
            }
            float gF = __shfl(g, 8 + lane);
            float gG = __shfl(g, 16 + lane);
            float gO = __shfl(g, 24 + lane);
            unsigned hv = 0;
            float cn = 0.f, hn = 0.f;
            if (lane < 8) {
                float gi = g  + xq0;
                float gf = gF + xq1;
                float gg = gG + xq2;
                float go = gO + xq3;
                float i_ = fsigm(gi);
                float f_ = fsigm(gf);
                float g_ = ftanh(gg);
                float o_ = fsigm(go);
                cn = f_ * creg + i_ * g_;
                hn = o_ * ftanh(cn);
                creg = cn;
                hv = (unsigned)f2bf(hn);
            }
            // publish: lane (<32) -> replica lane>>2, slot jj=lane&3 of this
            // block's EXCLUSIVE 64B line (base b*8). Plain relaxed store.
            {
                int jj = lane & 3;
                unsigned lo = (unsigned)__shfl((int)hv, 2 * jj);
                unsigned hi = (unsigned)__shfl((int)hv, 2 * jj + 1);
                if (lane < 32) {
                    unsigned long long wrd =
                        (((unsigned long long)(unsigned)(t + 1)) << 32)
                        | (unsigned long long)(lo | (hi << 16));
                    __hip_atomic_store(
                        &hcomm[(size_t)(t & 1) * 16384 + (size_t)(lane >> 2) * 2048 + b * 8 + jj],
                        wrd, __ATOMIC_RELAXED, __HIP_MEMORY_SCOPE_AGENT);
                }
            }
            __builtin_amdgcn_s_setprio(0);
            if (lane < 8) {
                hsb[(size_t)t * HID + b * 8 + lane] = (unsigned short)hv;
                if (t == SEQ - 1) {
                    outHC[b * 8 + lane] = hn;
                    outHC[HID + b * 8 + lane] = cn;
                }
            }
        }
    }
}

// ---------------- relu + log_softmax over rows of 256 ----------------
__global__ __launch_bounds__(256) void k_softmax(const float* __restrict__ logits,
                                                 float* __restrict__ out) {
    int row = blockIdx.x * 4 + (threadIdx.x >> 6);
    int lane = threadIdx.x & 63;
    const float* Lr = logits + (size_t)row * NL;
    float4 v = *(const float4*)&Lr[lane * 4];
    v.x = fmaxf(v.x, 0.f); v.y = fmaxf(v.y, 0.f);
    v.z = fmaxf(v.z, 0.f); v.w = fmaxf(v.w, 0.f);
    float m = fmaxf(fmaxf(v.x, v.y), fmaxf(v.z, v.w));
#pragma unroll
    for (int off = 32; off > 0; off >>= 1) m = fmaxf(m, __shfl_xor(m, off));
    float e = __expf(v.x - m) + __expf(v.y - m) + __expf(v.z - m) + __expf(v.w - m);
#pragma unroll
    for (int off = 32; off > 0; off >>= 1) e += __shfl_xor(e, off);
    float ls = __logf(e) + m;
    float4 o;
    o.x = v.x - ls; o.y = v.y - ls; o.z = v.z - ls; o.w = v.w - ls;
    *(float4*)&out[(size_t)row * NL + lane * 4] = o;
}

extern "C" void kernel_launch(void* const* d_in, const int* in_sizes, int n_in,
                              void* d_out, int out_size, void* d_ws, size_t ws_size,
                              hipStream_t stream) {
    const int*   ids   = (const int*)d_in[0];
    const float* h0    = (const float*)d_in[1];
    const float* c0    = (const float*)d_in[2];
    const float* W_emb = (const float*)d_in[3];
    const float* W_ih  = (const float*)d_in[4];
    const float* W_hh  = (const float*)d_in[5];
    const float* b_ih  = (const float*)d_in[6];
    const float* b_hh  = (const float*)d_in[7];
    const float* W_out = (const float*)d_in[8];
    const float* b_out = (const float*)d_in[9];
    float* out = (float*)d_out;

    char* ws = (char*)d_ws;
    unsigned short* xg    = (unsigned short*)(ws);                 // 64MB  [4096][2048u][4q] bf16
    unsigned short* hsb   = (unsigned short*)(ws + 67108864);      // 16MB  [4096,2048] bf16
    unsigned short* Wihb  = (unsigned short*)(ws + 83886080);      // 16MB
    unsigned short* embb  = (unsigned short*)(ws + 100663296);     // 8MB
    unsigned short* Woutb = (unsigned short*)(ws + 109051904);     // 1MB
    float*          logit = (float*)(ws + 110100480);              // 4MB
    unsigned short* Whhb  = (unsigned short*)(ws + 114294784);     // 32MB [8192,2048] bf16
    unsigned long long* hcomm = (unsigned long long*)(ws + 147849216); // 256KB (0xAA poison != any tag)

    k_f2b<<<(G4 * EMB / 4 + 255) / 256, 256, 0, stream>>>(W_ih, Wihb, G4 * EMB);
    k_f2b<<<(NL * HID / 4 + 255) / 256, 256, 0, stream>>>(W_out, Woutb, NL * HID);
    k_f2b<<<(G4 * HID / 4 + 255) / 256, 256, 0, stream>>>(W_hh, Whhb, G4 * HID);
    k_emb<<<SEQ, 256, 0, stream>>>(ids, W_emb, embb);

    dim3 g1(SEQ / BM, G4 / BN);
    k_gemm_bt<<<g1, 256, 0, stream>>>(embb, Wihb, b_ih, b_hh, nullptr, xg, SEQ, G4, EMB);

    hipFuncSetAttribute((const void*)k_lstm, hipFuncAttributeMaxDynamicSharedMemorySize, LSTM_LDS);
    k_lstm<<<256, 1024, LSTM_LDS, stream>>>(Whhb, xg, h0, c0, hsb, out + (size_t)SEQ * NL, hcomm);

    dim3 g2(SEQ / BM, NL / BN);
    k_gemm_bt<<<g2, 256, 0, stream>>>(hsb, Woutb, b_out, nullptr, logit, nullptr, SEQ, NL, HID);

    k_softmax<<<SEQ / 4, 256, 0, stream>>>(logit, out);
}